// Round 6
// baseline (108.152 us; speedup 1.0000x reference)
//
#include <hip/hip_runtime.h>

#define NTOK 16384
#define HID  4096
#define NEXP 64
#define BM   64
#define BK   256
#define NSTEPS (HID / BK)   // 16

typedef _Float16 f16;
typedef f16  f16x8 __attribute__((ext_vector_type(8)));
typedef float f32x4 __attribute__((ext_vector_type(4)));

// LDS planes: [row][256 k] f16 = 512 B/row = 32 units of 16 B.
// XOR unit low-3 bits with (row&7): fragment reads (16 rows, same unit)
// spread across all 8 bank-quads (R1-proven geometry, scaled up).
__device__ __forceinline__ int swz(int row, int u) {
    return row * 256 + ((u ^ (row & 7)) << 3);   // f16 elem offset
}

__global__ __launch_bounds__(512, 2)
void topk_gate_kernel(const float* __restrict__ x,
                      const float* __restrict__ w,
                      float* __restrict__ out) {
    __shared__ __align__(16) f16 Ah[BM * BK];    // 32 KB
    __shared__ __align__(16) f16 Al[BM * BK];    // 32 KB
    __shared__ __align__(16) f16 Bh[NEXP * BK];  // 32 KB
    __shared__ __align__(16) f16 Bl[NEXP * BK];  // 32 KB
    __shared__ float red[2][BM][4];

    const int t    = threadIdx.x;
    const int blk  = blockIdx.x;
    const int lane = t & 63;
    const int wid  = t >> 6;       // 0..7
    const int wm   = wid & 3;      // token quarter (16 tokens)
    const int wn   = wid >> 2;     // expert half (32 experts)
    const int col  = lane & 15;
    const int grp  = lane >> 4;

    // ---- staging role: threads 0-255 stage x (A), 256-511 stage w (B) ----
    // Each thread owns 64 CONSECUTIVE floats (256 B) of one row per step:
    // row visited in 1-KB contiguous chunks -> DRAM row-buffer friendly.
    const bool isB  = (t >= 256);
    const int  tt   = t & 255;
    const int  srow = tt >> 2;             // 0..63
    const int  q    = tt & 3;              // quarter of the row chunk
    const float scale = isB ? 64.0f : 1.0f;   // pow2: w_lo avoids fp16 subnormals
    const float* src = isB ? (w + (size_t)srow * HID + q * 64)
                           : (x + ((size_t)blk * BM + srow) * HID + q * 64);
    f16* dstH = isB ? Bh : Ah;
    f16* dstL = isB ? Bl : Al;

    f32x4 acc0 = {0.f, 0.f, 0.f, 0.f};   // experts wn*32 + col
    f32x4 acc1 = {0.f, 0.f, 0.f, 0.f};   // experts wn*32 + 16 + col

    // prologue: step-0 chunk (16 x float4 = 64 consecutive floats)
    float4 cur[16];
    #pragma unroll
    for (int i = 0; i < 16; ++i)
        cur[i] = *(const float4*)(src + i * 4);

    for (int s = 0; s < NSTEPS; ++s) {
        // issue next step's 256-B chunk early (full-step lead ~2.6 us >> HBM lat)
        const int sn = (s + 1 < NSTEPS) ? (s + 1) : s;
        float4 nxt[16];
        #pragma unroll
        for (int i = 0; i < 16; ++i)
            nxt[i] = *(const float4*)(src + (size_t)sn * BK + i * 4);

        __syncthreads();   // previous step's LDS reads complete

        // convert cur -> hi/lo f16 planes (8 units of 8 floats each)
        #pragma unroll
        for (int j = 0; j < 8; ++j) {
            float4 a = cur[2 * j], b = cur[2 * j + 1];
            float v[8] = {a.x, a.y, a.z, a.w, b.x, b.y, b.z, b.w};
            f16x8 hi, lo;
            #pragma unroll
            for (int u2 = 0; u2 < 8; ++u2) {
                float sv = v[u2] * scale;
                f16 h = (f16)sv;
                hi[u2] = h;
                lo[u2] = (f16)(sv - (float)h);
            }
            int off = swz(srow, q * 8 + j);
            *(f16x8*)&dstH[off] = hi;
            *(f16x8*)&dstL[off] = lo;
        }
        __syncthreads();   // planes visible

        // ---- compute: 8 K-subblocks of 32; 3-plane split-fp16 MFMA ----
        const int arow  = wm * 16 + col;
        const int brow0 = wn * 32 + col;
        const int brow1 = brow0 + 16;
        #pragma unroll
        for (int ks = 0; ks < 8; ++ks) {
            int u = ks * 4 + grp;
            f16x8 ah  = *(const f16x8*)&Ah[swz(arow,  u)];
            f16x8 al  = *(const f16x8*)&Al[swz(arow,  u)];
            f16x8 b0h = *(const f16x8*)&Bh[swz(brow0, u)];
            f16x8 b0l = *(const f16x8*)&Bl[swz(brow0, u)];
            f16x8 b1h = *(const f16x8*)&Bh[swz(brow1, u)];
            f16x8 b1l = *(const f16x8*)&Bl[swz(brow1, u)];
            acc0 = __builtin_amdgcn_mfma_f32_16x16x32_f16(ah, b0h, acc0, 0, 0, 0);
            acc0 = __builtin_amdgcn_mfma_f32_16x16x32_f16(ah, b0l, acc0, 0, 0, 0);
            acc0 = __builtin_amdgcn_mfma_f32_16x16x32_f16(al, b0h, acc0, 0, 0, 0);
            acc1 = __builtin_amdgcn_mfma_f32_16x16x32_f16(ah, b1h, acc1, 0, 0, 0);
            acc1 = __builtin_amdgcn_mfma_f32_16x16x32_f16(ah, b1l, acc1, 0, 0, 0);
            acc1 = __builtin_amdgcn_mfma_f32_16x16x32_f16(al, b1h, acc1, 0, 0, 0);
        }

        #pragma unroll
        for (int i = 0; i < 16; ++i) cur[i] = nxt[i];
    }

    // ---- epilogue: fused top-2 + softmax (R1-proven) ----
    // C layout: lane holds C[token = wm*16 + grp*4 + r][expert-in-half = col]
    #pragma unroll
    for (int r = 0; r < 4; ++r) {
        float va = acc0[r], vb = acc1[r];
        int   ia = wn * 32 + col, ib = ia + 16;
        float v0, v1; int i0, i1;
        if (va >= vb) { v0 = va; i0 = ia; v1 = vb; i1 = ib; }
        else          { v0 = vb; i0 = ib; v1 = va; i1 = ia; }
        #pragma unroll
        for (int m = 1; m <= 8; m <<= 1) {
            float ov0 = __shfl_xor(v0, m, 64);
            int   oi0 = __shfl_xor(i0, m, 64);
            float ov1 = __shfl_xor(v1, m, 64);
            int   oi1 = __shfl_xor(i1, m, 64);
            bool ob = (ov0 > v0) || (ov0 == v0 && oi0 < i0);
            if (ob) {
                bool k2 = (v0 > ov1) || (v0 == ov1 && i0 < oi1);
                v1 = k2 ? v0 : ov1; i1 = k2 ? i0 : oi1;
                v0 = ov0; i0 = oi0;
            } else {
                bool k2 = (ov0 > v1) || (ov0 == v1 && oi0 < i1);
                v1 = k2 ? ov0 : v1; i1 = k2 ? oi0 : i1;
            }
        }
        if (col == 0) {
            int tl = wm * 16 + grp * 4 + r;
            red[wn][tl][0] = v0; red[wn][tl][1] = (float)i0;
            red[wn][tl][2] = v1; red[wn][tl][3] = (float)i1;
        }
    }
    __syncthreads();

    if (t < BM) {
        float v0 = red[0][t][0]; int i0 = (int)red[0][t][1];
        float v1 = red[0][t][2]; int i1 = (int)red[0][t][3];
        float b0 = red[1][t][0]; int bi0 = (int)red[1][t][1];
        float b1 = red[1][t][2]; int bi1 = (int)red[1][t][3];
        bool bb = (b0 > v0) || (b0 == v0 && bi0 < i0);
        if (bb) {
            bool k2 = (v0 > b1) || (v0 == b1 && i0 < bi1);
            float nv1 = k2 ? v0 : b1; int ni1 = k2 ? i0 : bi1;
            v0 = b0; i0 = bi0; v1 = nv1; i1 = ni1;
        } else {
            bool k2 = (b0 > v1) || (b0 == v1 && bi0 < i1);
            v1 = k2 ? b0 : v1; i1 = k2 ? bi0 : i1;
        }
        // softmax over [v0, v1]; logits were scaled x64 via w
        float d  = (v1 - v0) * (1.0f / 64.0f);
        float e  = expf(d);
        float g0 = 1.0f / (1.0f + e);
        float g1 = e / (1.0f + e);

        int tok = blk * BM + t;
        out[(size_t)tok * 2 + 0] = g0;
        out[(size_t)tok * 2 + 1] = g1;
        out[(size_t)NTOK * 2 + (size_t)tok * 2 + 0] = (float)i0;
        out[(size_t)NTOK * 2 + (size_t)tok * 2 + 1] = (float)i1;
    }
}

extern "C" void kernel_launch(void* const* d_in, const int* in_sizes, int n_in,
                              void* d_out, int out_size, void* d_ws, size_t ws_size,
                              hipStream_t stream) {
    const float* x = (const float*)d_in[0];   // [16384, 4096] f32
    const float* w = (const float*)d_in[1];   // [64, 4096] f32
    float* out = (float*)d_out;               // gates [16384,2] then idx-as-f32 [16384,2]
    (void)in_sizes; (void)n_in; (void)out_size; (void)d_ws; (void)ws_size;

    topk_gate_kernel<<<dim3(NTOK / BM), dim3(512), 0, stream>>>(x, w, out);
}

// Round 7
// 74.225 us; speedup vs baseline: 1.4571x; 1.4571x over previous
//
#include <hip/hip_runtime.h>

#define NTOK 16384
#define HID  4096
#define NEXP 64
#define BM   32
#define BK   64
#define NSTEPS (HID / BK)   // 64

typedef _Float16 f16;
typedef f16  f16x8 __attribute__((ext_vector_type(8)));
typedef float f32x4 __attribute__((ext_vector_type(4)));

// LDS planes: [row][64 k] f16, 8 units of 16 B per row.
// XOR-swizzle unit with (row&7) (R1-proven): fragment reads spread across
// all 8 bank-quads -> 2-way aliasing = free.
__device__ __forceinline__ int swz(int row, int u) {
    return row * 64 + ((u ^ (row & 7)) << 3);
}

__global__ __launch_bounds__(256)
void topk_gate_kernel(const float* __restrict__ x,
                      const float* __restrict__ w,
                      float* __restrict__ out) {
    __shared__ __align__(16) f16 Ah[BM * BK];    // 4 KB
    __shared__ __align__(16) f16 Al[BM * BK];    // 4 KB
    __shared__ __align__(16) f16 Bh[NEXP * BK];  // 8 KB
    __shared__ __align__(16) f16 Bl[NEXP * BK];  // 8 KB
    __shared__ float red[2][BM][4];

    const int t    = threadIdx.x;
    const int blk  = blockIdx.x;
    const int lane = t & 63;
    const int wid  = t >> 6;       // 0..3
    const int wm   = wid & 1;      // token half (16 tokens)
    const int wn   = wid >> 1;     // expert half (32 experts)
    const int col  = lane & 15;
    const int grp  = lane >> 4;

    // ---- staging: EVERY thread stages 8 A-floats + 16 B-floats per step ----
    // A: 8 threads/row, 8 consecutive floats (one 16-B unit).
    const int  arow_s = t >> 3;            // 0..31
    const int  ao     = t & 7;             // unit
    const float* asrc = x + ((size_t)blk * BM + arow_s) * HID + ao * 8;
    // B: 4 threads/row, 16 consecutive floats (two units).
    const int  brow_s = t >> 2;            // 0..63
    const int  bq     = t & 3;
    const float* bsrc = w + (size_t)brow_s * HID + bq * 16;

    f32x4 acc0 = {0.f, 0.f, 0.f, 0.f};   // experts wn*32 + col
    f32x4 acc1 = {0.f, 0.f, 0.f, 0.f};   // experts wn*32 + 16 + col

    // prologue: step-0 loads (2 A float4s + 4 B float4s)
    float4 ca[2], cb[4];
    #pragma unroll
    for (int i = 0; i < 2; ++i) ca[i] = *(const float4*)(asrc + i * 4);
    #pragma unroll
    for (int i = 0; i < 4; ++i) cb[i] = *(const float4*)(bsrc + i * 4);

    for (int s = 0; s < NSTEPS; ++s) {
        // issue next step's loads early (1-step lead, R1-proven)
        const int sn = (s + 1 < NSTEPS) ? (s + 1) : s;
        float4 na[2], nb[4];
        #pragma unroll
        for (int i = 0; i < 2; ++i) na[i] = *(const float4*)(asrc + (size_t)sn * BK + i * 4);
        #pragma unroll
        for (int i = 0; i < 4; ++i) nb[i] = *(const float4*)(bsrc + (size_t)sn * BK + i * 4);

        __syncthreads();   // previous step's LDS reads complete

        // A: 8 floats -> one f16x8 unit per plane
        {
            float v[8] = {ca[0].x, ca[0].y, ca[0].z, ca[0].w,
                          ca[1].x, ca[1].y, ca[1].z, ca[1].w};
            f16x8 hi, lo;
            #pragma unroll
            for (int j = 0; j < 8; ++j) {
                f16 h = (f16)v[j];
                hi[j] = h;
                lo[j] = (f16)(v[j] - (float)h);
            }
            int off = swz(arow_s, ao);
            *(f16x8*)&Ah[off] = hi;
            *(f16x8*)&Al[off] = lo;
        }
        // B: 16 floats (x64 scale, exact pow2 -> lo avoids subnormals) -> two units
        #pragma unroll
        for (int j2 = 0; j2 < 2; ++j2) {
            float4 a = cb[2 * j2], b = cb[2 * j2 + 1];
            float v[8] = {a.x, a.y, a.z, a.w, b.x, b.y, b.z, b.w};
            f16x8 hi, lo;
            #pragma unroll
            for (int j = 0; j < 8; ++j) {
                float sv = v[j] * 64.0f;
                f16 h = (f16)sv;
                hi[j] = h;
                lo[j] = (f16)(sv - (float)h);
            }
            int off = swz(brow_s, 2 * bq + j2);
            *(f16x8*)&Bh[off] = hi;
            *(f16x8*)&Bl[off] = lo;
        }
        __syncthreads();   // planes visible

        // ---- compute: 2 K-subblocks of 32; 3-plane split-fp16 MFMA ----
        const int arow  = wm * 16 + col;
        const int brow0 = wn * 32 + col;
        const int brow1 = brow0 + 16;
        #pragma unroll
        for (int ks = 0; ks < 2; ++ks) {
            int u = ks * 4 + grp;
            f16x8 ah  = *(const f16x8*)&Ah[swz(arow,  u)];
            f16x8 al  = *(const f16x8*)&Al[swz(arow,  u)];
            f16x8 b0h = *(const f16x8*)&Bh[swz(brow0, u)];
            f16x8 b0l = *(const f16x8*)&Bl[swz(brow0, u)];
            f16x8 b1h = *(const f16x8*)&Bh[swz(brow1, u)];
            f16x8 b1l = *(const f16x8*)&Bl[swz(brow1, u)];
            acc0 = __builtin_amdgcn_mfma_f32_16x16x32_f16(ah, b0h, acc0, 0, 0, 0);
            acc0 = __builtin_amdgcn_mfma_f32_16x16x32_f16(ah, b0l, acc0, 0, 0, 0);
            acc0 = __builtin_amdgcn_mfma_f32_16x16x32_f16(al, b0h, acc0, 0, 0, 0);
            acc1 = __builtin_amdgcn_mfma_f32_16x16x32_f16(ah, b1h, acc1, 0, 0, 0);
            acc1 = __builtin_amdgcn_mfma_f32_16x16x32_f16(ah, b1l, acc1, 0, 0, 0);
            acc1 = __builtin_amdgcn_mfma_f32_16x16x32_f16(al, b1h, acc1, 0, 0, 0);
        }

        #pragma unroll
        for (int i = 0; i < 2; ++i) ca[i] = na[i];
        #pragma unroll
        for (int i = 0; i < 4; ++i) cb[i] = nb[i];
    }

    // ---- epilogue: fused top-2 + softmax (R1-proven) ----
    // C layout: lane holds C[token = wm*16 + grp*4 + r][expert-in-half = col]
    #pragma unroll
    for (int r = 0; r < 4; ++r) {
        float va = acc0[r], vb = acc1[r];
        int   ia = wn * 32 + col, ib = ia + 16;
        float v0, v1; int i0, i1;
        if (va >= vb) { v0 = va; i0 = ia; v1 = vb; i1 = ib; }
        else          { v0 = vb; i0 = ib; v1 = va; i1 = ia; }
        #pragma unroll
        for (int m = 1; m <= 8; m <<= 1) {
            float ov0 = __shfl_xor(v0, m, 64);
            int   oi0 = __shfl_xor(i0, m, 64);
            float ov1 = __shfl_xor(v1, m, 64);
            int   oi1 = __shfl_xor(i1, m, 64);
            bool ob = (ov0 > v0) || (ov0 == v0 && oi0 < i0);
            if (ob) {
                bool k2 = (v0 > ov1) || (v0 == ov1 && i0 < oi1);
                v1 = k2 ? v0 : ov1; i1 = k2 ? i0 : oi1;
                v0 = ov0; i0 = oi0;
            } else {
                bool k2 = (ov0 > v1) || (ov0 == v1 && oi0 < i1);
                v1 = k2 ? ov0 : v1; i1 = k2 ? oi0 : i1;
            }
        }
        if (col == 0) {
            int tl = wm * 16 + grp * 4 + r;
            red[wn][tl][0] = v0; red[wn][tl][1] = (float)i0;
            red[wn][tl][2] = v1; red[wn][tl][3] = (float)i1;
        }
    }
    __syncthreads();

    if (t < BM) {
        float v0 = red[0][t][0]; int i0 = (int)red[0][t][1];
        float v1 = red[0][t][2]; int i1 = (int)red[0][t][3];
        float b0 = red[1][t][0]; int bi0 = (int)red[1][t][1];
        float b1 = red[1][t][2]; int bi1 = (int)red[1][t][3];
        bool bb = (b0 > v0) || (b0 == v0 && bi0 < i0);
        if (bb) {
            bool k2 = (v0 > b1) || (v0 == b1 && i0 < bi1);
            float nv1 = k2 ? v0 : b1; int ni1 = k2 ? i0 : bi1;
            v0 = b0; i0 = bi0; v1 = nv1; i1 = ni1;
        } else {
            bool k2 = (b0 > v1) || (b0 == v1 && bi0 < i1);
            v1 = k2 ? b0 : v1; i1 = k2 ? bi0 : i1;
        }
        // softmax over [v0, v1]; logits were scaled x64 via w
        float d  = (v1 - v0) * (1.0f / 64.0f);
        float e  = expf(d);
        float g0 = 1.0f / (1.0f + e);
        float g1 = e / (1.0f + e);

        int tok = blk * BM + t;
        out[(size_t)tok * 2 + 0] = g0;
        out[(size_t)tok * 2 + 1] = g1;
        out[(size_t)NTOK * 2 + (size_t)tok * 2 + 0] = (float)i0;
        out[(size_t)NTOK * 2 + (size_t)tok * 2 + 1] = (float)i1;
    }
}

extern "C" void kernel_launch(void* const* d_in, const int* in_sizes, int n_in,
                              void* d_out, int out_size, void* d_ws, size_t ws_size,
                              hipStream_t stream) {
    const float* x = (const float*)d_in[0];   // [16384, 4096] f32
    const float* w = (const float*)d_in[1];   // [64, 4096] f32
    float* out = (float*)d_out;               // gates [16384,2] then idx-as-f32 [16384,2]
    (void)in_sizes; (void)n_in; (void)out_size; (void)d_ws; (void)ws_size;

    topk_gate_kernel<<<dim3(NTOK / BM), dim3(256), 0, stream>>>(x, w, out);
}

// Round 8
// 68.475 us; speedup vs baseline: 1.5794x; 1.0840x over previous
//
#include <hip/hip_runtime.h>

#define NTOK 16384
#define HID  4096
#define NEXP 64
#define BM   64
#define BK   64
#define NSTEPS (HID / BK)   // 64

typedef _Float16 f16;
typedef f16  f16x8 __attribute__((ext_vector_type(8)));
typedef float f32x4 __attribute__((ext_vector_type(4)));

// LDS planes: [row][64 k] f16, 8 units of 16 B per row, XOR-swizzled (R1-proven):
// fragment reads (16 rows, fixed unit) spread across all 8 bank-quads.
__device__ __forceinline__ int swz(int row, int u) {
    return row * 64 + ((u ^ (row & 7)) << 3);
}

__global__ __launch_bounds__(512)
void topk_gate_kernel(const float* __restrict__ x,
                      const float* __restrict__ w,
                      float* __restrict__ out) {
    __shared__ __align__(16) f16 Ah[2][BM * BK];     // 16 KB (double-buffered)
    __shared__ __align__(16) f16 Al[2][BM * BK];     // 16 KB
    __shared__ __align__(16) f16 Bh[2][NEXP * BK];   // 16 KB
    __shared__ __align__(16) f16 Bl[2][NEXP * BK];   // 16 KB
    __shared__ f32x4 red2[4][4][64];                 // 16 KB K-reduce buffer
    __shared__ float red[2][BM][4];

    const int t    = threadIdx.x;
    const int blk  = blockIdx.x;
    const int lane = t & 63;
    const int wid  = t >> 6;        // 0..7
    const int col  = lane & 15;
    const int grp  = lane >> 4;
    // wave tile: quadrant q (qm: token half of 64, qn: expert half), kh: K-half of step
    const int kh   = wid >> 2;      // 0..1
    const int q    = wid & 3;
    const int qm   = q & 1;
    const int qn   = q >> 1;

    // ---- staging (R1-proven): threads 0-255 stage x, 256-511 stage w ----
    // 4 threads/row, 16 consecutive floats each.
    const bool isB  = (t >= 256);
    const int  tt   = t & 255;
    const int  srow = tt >> 2;             // 0..63
    const int  sq   = tt & 3;
    const float scale = isB ? 64.0f : 1.0f;   // pow2: w_lo avoids fp16 subnormals
    const float* src = isB ? (w + (size_t)srow * HID + sq * 16)
                           : (x + ((size_t)blk * BM + srow) * HID + sq * 16);

    // fragment read offsets: A rows qm*32+tm2*16+col, B rows qn*32+en2*16+col,
    // k-chunk unit = kh*4 + grp
    int aoff[2], boff[2];
    #pragma unroll
    for (int i = 0; i < 2; ++i) {
        aoff[i] = swz(qm * 32 + i * 16 + col, kh * 4 + grp);
        boff[i] = swz(qn * 32 + i * 16 + col, kh * 4 + grp);
    }

    f32x4 acc[2][2];
    #pragma unroll
    for (int i = 0; i < 2; ++i)
        #pragma unroll
        for (int j = 0; j < 2; ++j)
            acc[i][j] = (f32x4){0.f, 0.f, 0.f, 0.f};

    float4 cur[4], nxt[4];

    // convert 16 staged floats (cur) -> hi/lo f16 units in buffer p
    #define CONVERT(p_) do {                                                   \
        f16* dh_ = isB ? Bh[p_] : Ah[p_];                                      \
        f16* dl_ = isB ? Bl[p_] : Al[p_];                                      \
        _Pragma("unroll")                                                      \
        for (int h = 0; h < 2; ++h) {                                          \
            float4 a_ = cur[2 * h], b_ = cur[2 * h + 1];                       \
            float v_[8] = {a_.x, a_.y, a_.z, a_.w, b_.x, b_.y, b_.z, b_.w};    \
            f16x8 hi_, lo_;                                                    \
            _Pragma("unroll")                                                  \
            for (int j = 0; j < 8; ++j) {                                      \
                float sv_ = v_[j] * scale;                                     \
                f16 h16_ = (f16)sv_;                                           \
                hi_[j] = h16_;                                                 \
                lo_[j] = (f16)(sv_ - (float)h16_);                             \
            }                                                                  \
            int off_ = swz(srow, sq * 2 + h);                                  \
            *(f16x8*)&dh_[off_] = hi_;                                         \
            *(f16x8*)&dl_[off_] = lo_;                                         \
        }                                                                      \
    } while (0)

    // ---- prologue: step0 -> buf0; step1 into registers ----
    #pragma unroll
    for (int i = 0; i < 4; ++i) cur[i] = *(const float4*)(src + i * 4);
    CONVERT(0);
    #pragma unroll
    for (int i = 0; i < 4; ++i) cur[i] = *(const float4*)(src + BK + i * 4);
    __syncthreads();

    // ---- main loop: ONE barrier/step; convert->buf^1 overlaps compute<-buf ----
    for (int s = 0; s < NSTEPS; ++s) {
        const int sn = (s + 2 < NSTEPS) ? (s + 2) : (NSTEPS - 1);
        #pragma unroll
        for (int i = 0; i < 4; ++i)
            nxt[i] = *(const float4*)(src + (size_t)sn * BK + i * 4);

        if (s + 1 < NSTEPS) CONVERT((s + 1) & 1);

        const int p = s & 1;
        f16x8 A0h = *(const f16x8*)&Ah[p][aoff[0]];
        f16x8 A0l = *(const f16x8*)&Al[p][aoff[0]];
        f16x8 A1h = *(const f16x8*)&Ah[p][aoff[1]];
        f16x8 A1l = *(const f16x8*)&Al[p][aoff[1]];
        f16x8 B0h = *(const f16x8*)&Bh[p][boff[0]];
        f16x8 B0l = *(const f16x8*)&Bl[p][boff[0]];
        f16x8 B1h = *(const f16x8*)&Bh[p][boff[1]];
        f16x8 B1l = *(const f16x8*)&Bl[p][boff[1]];

        acc[0][0] = __builtin_amdgcn_mfma_f32_16x16x32_f16(A0h, B0h, acc[0][0], 0, 0, 0);
        acc[0][0] = __builtin_amdgcn_mfma_f32_16x16x32_f16(A0h, B0l, acc[0][0], 0, 0, 0);
        acc[0][0] = __builtin_amdgcn_mfma_f32_16x16x32_f16(A0l, B0h, acc[0][0], 0, 0, 0);
        acc[0][1] = __builtin_amdgcn_mfma_f32_16x16x32_f16(A0h, B1h, acc[0][1], 0, 0, 0);
        acc[0][1] = __builtin_amdgcn_mfma_f32_16x16x32_f16(A0h, B1l, acc[0][1], 0, 0, 0);
        acc[0][1] = __builtin_amdgcn_mfma_f32_16x16x32_f16(A0l, B1h, acc[0][1], 0, 0, 0);
        acc[1][0] = __builtin_amdgcn_mfma_f32_16x16x32_f16(A1h, B0h, acc[1][0], 0, 0, 0);
        acc[1][0] = __builtin_amdgcn_mfma_f32_16x16x32_f16(A1h, B0l, acc[1][0], 0, 0, 0);
        acc[1][0] = __builtin_amdgcn_mfma_f32_16x16x32_f16(A1l, B0h, acc[1][0], 0, 0, 0);
        acc[1][1] = __builtin_amdgcn_mfma_f32_16x16x32_f16(A1h, B1h, acc[1][1], 0, 0, 0);
        acc[1][1] = __builtin_amdgcn_mfma_f32_16x16x32_f16(A1h, B1l, acc[1][1], 0, 0, 0);
        acc[1][1] = __builtin_amdgcn_mfma_f32_16x16x32_f16(A1l, B1h, acc[1][1], 0, 0, 0);

        __syncthreads();
        #pragma unroll
        for (int i = 0; i < 4; ++i) cur[i] = nxt[i];
    }

    // ---- K-reduce: waves 4-7 (kh=1) hand partial accs to waves 0-3 ----
    if (wid >= 4) {
        #pragma unroll
        for (int i = 0; i < 2; ++i)
            #pragma unroll
            for (int j = 0; j < 2; ++j)
                red2[wid - 4][i * 2 + j][lane] = acc[i][j];
    }
    __syncthreads();
    if (wid < 4) {
        #pragma unroll
        for (int i = 0; i < 2; ++i)
            #pragma unroll
            for (int j = 0; j < 2; ++j)
                acc[i][j] += red2[wid][i * 2 + j][lane];

        // ---- per-wave top-2 over its 32 experts (en2-merge + 4-level butterfly) ----
        #pragma unroll
        for (int tm2 = 0; tm2 < 2; ++tm2)
            #pragma unroll
            for (int r = 0; r < 4; ++r) {
                float va = acc[tm2][0][r], vb = acc[tm2][1][r];
                int   ia = qn * 32 + col, ib = ia + 16;
                float v0, v1; int i0, i1;
                if (va >= vb) { v0 = va; i0 = ia; v1 = vb; i1 = ib; }
                else          { v0 = vb; i0 = ib; v1 = va; i1 = ia; }
                #pragma unroll
                for (int m = 1; m <= 8; m <<= 1) {
                    float ov0 = __shfl_xor(v0, m, 64);
                    int   oi0 = __shfl_xor(i0, m, 64);
                    float ov1 = __shfl_xor(v1, m, 64);
                    int   oi1 = __shfl_xor(i1, m, 64);
                    bool ob = (ov0 > v0) || (ov0 == v0 && oi0 < i0);
                    if (ob) {
                        bool k2 = (v0 > ov1) || (v0 == ov1 && i0 < oi1);
                        v1 = k2 ? v0 : ov1; i1 = k2 ? i0 : oi1;
                        v0 = ov0; i0 = oi0;
                    } else {
                        bool k2 = (ov0 > v1) || (ov0 == v1 && oi0 < i1);
                        v1 = k2 ? ov0 : v1; i1 = k2 ? oi0 : i1;
                    }
                }
                if (col == 0) {
                    int tl = qm * 32 + tm2 * 16 + grp * 4 + r;
                    red[qn][tl][0] = v0; red[qn][tl][1] = (float)i0;
                    red[qn][tl][2] = v1; red[qn][tl][3] = (float)i1;
                }
            }
    }
    __syncthreads();

    if (t < BM) {
        float v0 = red[0][t][0]; int i0 = (int)red[0][t][1];
        float v1 = red[0][t][2]; int i1 = (int)red[0][t][3];
        float b0 = red[1][t][0]; int bi0 = (int)red[1][t][1];
        float b1 = red[1][t][2]; int bi1 = (int)red[1][t][3];
        bool bb = (b0 > v0) || (b0 == v0 && bi0 < i0);
        if (bb) {
            bool k2 = (v0 > b1) || (v0 == b1 && i0 < bi1);
            float nv1 = k2 ? v0 : b1; int ni1 = k2 ? i0 : bi1;
            v0 = b0; i0 = bi0; v1 = nv1; i1 = ni1;
        } else {
            bool k2 = (b0 > v1) || (b0 == v1 && bi0 < i1);
            v1 = k2 ? b0 : v1; i1 = k2 ? bi0 : i1;
        }
        // softmax over [v0, v1]; logits were scaled x64 via w
        float d  = (v1 - v0) * (1.0f / 64.0f);
        float e  = expf(d);
        float g0 = 1.0f / (1.0f + e);
        float g1 = e / (1.0f + e);

        int tok = blk * BM + t;
        out[(size_t)tok * 2 + 0] = g0;
        out[(size_t)tok * 2 + 1] = g1;
        out[(size_t)NTOK * 2 + (size_t)tok * 2 + 0] = (float)i0;
        out[(size_t)NTOK * 2 + (size_t)tok * 2 + 1] = (float)i1;
    }
}

extern "C" void kernel_launch(void* const* d_in, const int* in_sizes, int n_in,
                              void* d_out, int out_size, void* d_ws, size_t ws_size,
                              hipStream_t stream) {
    const float* x = (const float*)d_in[0];   // [16384, 4096] f32
    const float* w = (const float*)d_in[1];   // [64, 4096] f32
    float* out = (float*)d_out;               // gates [16384,2] then idx-as-f32 [16384,2]
    (void)in_sizes; (void)n_in; (void)out_size; (void)d_ws; (void)ws_size;

    topk_gate_kernel<<<dim3(NTOK / BM), dim3(512), 0, stream>>>(x, w, out);
}